// Round 9
// baseline (57.809 us; speedup 1.0000x reference)
//
#include <hip/hip_runtime.h>
#include <math.h>

// GaussianNLLLoss: out = -mean( c0 + log(normcdf(-lambda*resid/sigma)) - resid^2/(2*sigma2) )
// R9: R6 (best, 51.7us) + NONTEMPORAL loads on yp only.
// R3-R8 lesson: every load structure lands at 52-56us; MLP arithmetic says
// latency isn't binding (need 8KB/CU in flight, have 28KB). Effective read
// stream = 5.6 TB/s = 89% of the 6.29 TB/s copy ceiling, with FETCH_SIZE
// pinned at exactly one tensor (134MB): 268MB working set thrashes the
// 256MiB LLC at ~50% hit. NT-streaming yp keeps yt fully LLC-resident ->
// tests whether IF$ and HBM delivery paths have independent headroom.

typedef float f32x4 __attribute__((ext_vector_type(4)));

__device__ __forceinline__ float ll_elem(float r, float karg, float nk2, float inv2s2) {
    float r2 = r * r;
    float x  = karg * r;
    float ax = fabsf(x);
    float t  = __builtin_amdgcn_rcpf(fmaf(0.3275911f, ax, 1.0f));  // v_rcp_f32
    float p  = fmaf(t, 1.061405429f, -1.453152027f);
    p = fmaf(t, p, 1.421413741f);
    p = fmaf(t, p, -0.284496736f);
    p = fmaf(t, p, 0.254829592f);
    p *= t;
    float e  = __expf(nk2 * r2);                 // exp(-x^2), reusing r^2
    float ea = fmaf(-p, e, 1.0f);                // erf(|x|)  (A&S 7.1.26, |err|<1.5e-7)
    float ev = copysignf(ea, x);                 // erf(x)
    return __logf(fmaf(0.5f, ev, 0.5f)) - r2 * inv2s2;  // log(ncdf) - r^2/(2s2)
}

__global__ __launch_bounds__(256) void gnll_stage1(
    const f32x4* __restrict__ yp, const f32x4* __restrict__ yt,
    const float* __restrict__ lsv, const float* __restrict__ lsu,
    float* __restrict__ partials, int n4)
{
    const float std_v  = __expf(lsv[0]);
    const float std_u  = __expf(lsu[0]);
    const float sigma2 = std_v * std_v + std_u * std_u;
    const float sigma  = sqrtf(sigma2);
    const float llamda = std_u / std_v;
    const float karg   = -llamda / sigma * 0.70710678118654752f;  // *r -> erf arg
    const float nk2    = -karg * karg;                            // *r^2 -> -x^2
    const float c0     = -0.5f * logf(1.57079632679489662f)
                         - 0.5f * logf(sigma2);
    const float inv2s2 = 0.5f / sigma2;

    float acc = 0.0f;
    int   cnt = 0;
    const int tid = blockIdx.x * blockDim.x + threadIdx.x;
    const int nth = gridDim.x * blockDim.x;

    f32x4 pA0, pA1, pA2, pA3, tA0, tA1, tA2, tA3;
    f32x4 pB0, pB1, pB2, pB3, tB0, tB1, tB2, tB3;

// yp: nontemporal (stream, don't allocate in L2/LLC). yt: regular (LLC-resident).
#define LOAD_A(g) { int b_ = (g) * nth * 4 + tid;                                   \
    pA0 = __builtin_nontemporal_load(yp + b_);                                      \
    pA1 = __builtin_nontemporal_load(yp + b_ + nth);                                \
    pA2 = __builtin_nontemporal_load(yp + b_ + 2*nth);                              \
    pA3 = __builtin_nontemporal_load(yp + b_ + 3*nth);                              \
    tA0 = yt[b_]; tA1 = yt[b_ + nth]; tA2 = yt[b_ + 2*nth]; tA3 = yt[b_ + 3*nth]; }
#define LOAD_B(g) { int b_ = (g) * nth * 4 + tid;                                   \
    pB0 = __builtin_nontemporal_load(yp + b_);                                      \
    pB1 = __builtin_nontemporal_load(yp + b_ + nth);                                \
    pB2 = __builtin_nontemporal_load(yp + b_ + 2*nth);                              \
    pB3 = __builtin_nontemporal_load(yp + b_ + 3*nth);                              \
    tB0 = yt[b_]; tB1 = yt[b_ + nth]; tB2 = yt[b_ + 2*nth]; tB3 = yt[b_ + 3*nth]; }
#define COMP1(P, T) { float s_ =                                                    \
      ll_elem(T.x - P.x, karg, nk2, inv2s2) + ll_elem(T.y - P.y, karg, nk2, inv2s2) \
    + ll_elem(T.z - P.z, karg, nk2, inv2s2) + ll_elem(T.w - P.w, karg, nk2, inv2s2);\
    acc += s_; }
#define COMP_A { COMP1(pA0, tA0) COMP1(pA1, tA1) COMP1(pA2, tA2) COMP1(pA3, tA3) cnt += 16; }
#define COMP_B { COMP1(pB0, tB0) COMP1(pB1, tB1) COMP1(pB2, tB2) COMP1(pB3, tB3) cnt += 16; }

    const int ngroups = n4 / (nth * 4);   // 4 for the bench shape
    if (ngroups > 0) {
        LOAD_A(0)
        int g = 0;
        for (; g + 2 < ngroups; g += 2) {
            LOAD_B(g + 1)
            COMP_A
            LOAD_A(g + 2)
            COMP_B
        }
        if (g + 1 < ngroups) {
            LOAD_B(g + 1)
            COMP_A
            COMP_B
        } else {
            COMP_A
        }
    }

    // Tail (none at the bench shape)
    for (int i = ngroups * nth * 4 + tid; i < n4; i += nth) {
        f32x4 p = __builtin_nontemporal_load(yp + i);
        f32x4 t = yt[i];
        acc += ll_elem(t.x - p.x, karg, nk2, inv2s2)
             + ll_elem(t.y - p.y, karg, nk2, inv2s2)
             + ll_elem(t.z - p.z, karg, nk2, inv2s2)
             + ll_elem(t.w - p.w, karg, nk2, inv2s2);
        cnt += 4;
    }

    acc = fmaf((float)cnt, c0, acc);

    // wave64 butterfly reduce
    #pragma unroll
    for (int off = 32; off > 0; off >>= 1)
        acc += __shfl_down(acc, off, 64);

    __shared__ float ws[4];
    int lane = threadIdx.x & 63;
    int wid  = threadIdx.x >> 6;
    if (lane == 0) ws[wid] = acc;
    __syncthreads();
    if (threadIdx.x == 0)
        partials[blockIdx.x] = (ws[0] + ws[1]) + (ws[2] + ws[3]);
}

__global__ __launch_bounds__(256) void gnll_stage2(
    const float* __restrict__ partials, float* __restrict__ out,
    int nparts, float neg_inv_n)
{
    float acc = 0.0f;
    for (int i = threadIdx.x; i < nparts; i += 256)
        acc += partials[i];

    #pragma unroll
    for (int off = 32; off > 0; off >>= 1)
        acc += __shfl_down(acc, off, 64);

    __shared__ float ws[4];
    int lane = threadIdx.x & 63;
    int wid  = threadIdx.x >> 6;
    if (lane == 0) ws[wid] = acc;
    __syncthreads();
    if (threadIdx.x == 0)
        out[0] = ((ws[0] + ws[1]) + (ws[2] + ws[3])) * neg_inv_n;
}

extern "C" void kernel_launch(void* const* d_in, const int* in_sizes, int n_in,
                              void* d_out, int out_size, void* d_ws, size_t ws_size,
                              hipStream_t stream) {
    const f32x4* yp = (const f32x4*)d_in[0];
    const f32x4* yt = (const f32x4*)d_in[1];
    const float* lsv = (const float*)d_in[2];
    const float* lsu = (const float*)d_in[3];
    float* out = (float*)d_out;
    float* partials = (float*)d_ws;   // 2048 floats = 8 KB scratch

    long long n = (long long)in_sizes[0];   // 33554432, divisible by 4
    int n4 = (int)(n / 4);
    float neg_inv_n = -1.0f / (float)n;

    const int block = 256;
    const int grid  = 2048;  // ngroups = 4 at bench shape, no tail
    gnll_stage1<<<grid, block, 0, stream>>>(yp, yt, lsv, lsu, partials, n4);
    gnll_stage2<<<1, block, 0, stream>>>(partials, out, grid, neg_inv_n);
}

// Round 10
// 54.000 us; speedup vs baseline: 1.0705x; 1.0705x over previous
//
#include <hip/hip_runtime.h>
#include <math.h>

// GaussianNLLLoss: out = -mean( c0 + log(normcdf(-lambda*resid/sigma)) - resid^2/(2*sigma2) )
// R10 = R6 revert (best: 51.7us). Final state after R1-R9 exploration:
//  - fast transcendentals (A&S erf + v_exp/v_log): VALU 39->27% (R2)
//  - two-stage reduction, zero same-address atomics: -6.3us (R6)
//  - structural levers all null: MLP batching (R3), reg double-buffer (R4,
//    compiler collapses), one-shot (R5/R7), asm counted-vmcnt (R8),
//    NT cache-split (R9: FETCH unchanged 134MB, slower -> common fabric path).
// Achieved: 268MB read in ~48us stage1 = 5.6 TB/s ~= 89% of the 6.29 TB/s
// measured copy ceiling on a 268MB-on-256MiB LLC-thrashing mixed stream.

__device__ __forceinline__ float ll_elem(float r, float karg, float nk2, float inv2s2) {
    float r2 = r * r;
    float x  = karg * r;
    float ax = fabsf(x);
    float t  = __builtin_amdgcn_rcpf(fmaf(0.3275911f, ax, 1.0f));  // v_rcp_f32
    float p  = fmaf(t, 1.061405429f, -1.453152027f);
    p = fmaf(t, p, 1.421413741f);
    p = fmaf(t, p, -0.284496736f);
    p = fmaf(t, p, 0.254829592f);
    p *= t;
    float e  = __expf(nk2 * r2);                 // exp(-x^2), reusing r^2
    float ea = fmaf(-p, e, 1.0f);                // erf(|x|)  (A&S 7.1.26, |err|<1.5e-7)
    float ev = copysignf(ea, x);                 // erf(x)
    return __logf(fmaf(0.5f, ev, 0.5f)) - r2 * inv2s2;  // log(ncdf) - r^2/(2s2)
}

__global__ __launch_bounds__(256) void gnll_stage1(
    const float4* __restrict__ yp, const float4* __restrict__ yt,
    const float* __restrict__ lsv, const float* __restrict__ lsu,
    float* __restrict__ partials, int n4)
{
    const float std_v  = __expf(lsv[0]);
    const float std_u  = __expf(lsu[0]);
    const float sigma2 = std_v * std_v + std_u * std_u;
    const float sigma  = sqrtf(sigma2);
    const float llamda = std_u / std_v;
    const float karg   = -llamda / sigma * 0.70710678118654752f;  // *r -> erf arg
    const float nk2    = -karg * karg;                            // *r^2 -> -x^2
    const float c0     = -0.5f * logf(1.57079632679489662f)
                         - 0.5f * logf(sigma2);
    const float inv2s2 = 0.5f / sigma2;

    float acc = 0.0f;
    int   cnt = 0;
    const int tid = blockIdx.x * blockDim.x + threadIdx.x;
    const int nth = gridDim.x * blockDim.x;

    float4 pA0, pA1, pA2, pA3, tA0, tA1, tA2, tA3;
    float4 pB0, pB1, pB2, pB3, tB0, tB1, tB2, tB3;

#define LOAD_A(g) { int b_ = (g) * nth * 4 + tid;                                   \
    pA0 = yp[b_]; pA1 = yp[b_ + nth]; pA2 = yp[b_ + 2*nth]; pA3 = yp[b_ + 3*nth];   \
    tA0 = yt[b_]; tA1 = yt[b_ + nth]; tA2 = yt[b_ + 2*nth]; tA3 = yt[b_ + 3*nth]; }
#define LOAD_B(g) { int b_ = (g) * nth * 4 + tid;                                   \
    pB0 = yp[b_]; pB1 = yp[b_ + nth]; pB2 = yp[b_ + 2*nth]; pB3 = yp[b_ + 3*nth];   \
    tB0 = yt[b_]; tB1 = yt[b_ + nth]; tB2 = yt[b_ + 2*nth]; tB3 = yt[b_ + 3*nth]; }
#define COMP1(P, T) { float s_ =                                                    \
      ll_elem(T.x - P.x, karg, nk2, inv2s2) + ll_elem(T.y - P.y, karg, nk2, inv2s2) \
    + ll_elem(T.z - P.z, karg, nk2, inv2s2) + ll_elem(T.w - P.w, karg, nk2, inv2s2);\
    acc += s_; }
#define COMP_A { COMP1(pA0, tA0) COMP1(pA1, tA1) COMP1(pA2, tA2) COMP1(pA3, tA3) cnt += 16; }
#define COMP_B { COMP1(pB0, tB0) COMP1(pB1, tB1) COMP1(pB2, tB2) COMP1(pB3, tB3) cnt += 16; }

    const int ngroups = n4 / (nth * 4);   // 4 for the bench shape
    if (ngroups > 0) {
        LOAD_A(0)
        int g = 0;
        for (; g + 2 < ngroups; g += 2) {
            LOAD_B(g + 1)
            COMP_A
            LOAD_A(g + 2)
            COMP_B
        }
        if (g + 1 < ngroups) {
            LOAD_B(g + 1)
            COMP_A
            COMP_B
        } else {
            COMP_A
        }
    }

    // Tail (none at the bench shape)
    for (int i = ngroups * nth * 4 + tid; i < n4; i += nth) {
        float4 p = yp[i];
        float4 t = yt[i];
        acc += ll_elem(t.x - p.x, karg, nk2, inv2s2)
             + ll_elem(t.y - p.y, karg, nk2, inv2s2)
             + ll_elem(t.z - p.z, karg, nk2, inv2s2)
             + ll_elem(t.w - p.w, karg, nk2, inv2s2);
        cnt += 4;
    }

    acc = fmaf((float)cnt, c0, acc);

    // wave64 butterfly reduce
    #pragma unroll
    for (int off = 32; off > 0; off >>= 1)
        acc += __shfl_down(acc, off, 64);

    __shared__ float ws[4];
    int lane = threadIdx.x & 63;
    int wid  = threadIdx.x >> 6;
    if (lane == 0) ws[wid] = acc;
    __syncthreads();
    if (threadIdx.x == 0)
        partials[blockIdx.x] = (ws[0] + ws[1]) + (ws[2] + ws[3]);
}

__global__ __launch_bounds__(256) void gnll_stage2(
    const float* __restrict__ partials, float* __restrict__ out,
    int nparts, float neg_inv_n)
{
    float acc = 0.0f;
    for (int i = threadIdx.x; i < nparts; i += 256)
        acc += partials[i];

    #pragma unroll
    for (int off = 32; off > 0; off >>= 1)
        acc += __shfl_down(acc, off, 64);

    __shared__ float ws[4];
    int lane = threadIdx.x & 63;
    int wid  = threadIdx.x >> 6;
    if (lane == 0) ws[wid] = acc;
    __syncthreads();
    if (threadIdx.x == 0)
        out[0] = ((ws[0] + ws[1]) + (ws[2] + ws[3])) * neg_inv_n;
}

extern "C" void kernel_launch(void* const* d_in, const int* in_sizes, int n_in,
                              void* d_out, int out_size, void* d_ws, size_t ws_size,
                              hipStream_t stream) {
    const float4* yp = (const float4*)d_in[0];
    const float4* yt = (const float4*)d_in[1];
    const float* lsv = (const float*)d_in[2];
    const float* lsu = (const float*)d_in[3];
    float* out = (float*)d_out;
    float* partials = (float*)d_ws;   // 2048 floats = 8 KB scratch

    long long n = (long long)in_sizes[0];   // 33554432, divisible by 4
    int n4 = (int)(n / 4);
    float neg_inv_n = -1.0f / (float)n;

    const int block = 256;
    const int grid  = 2048;  // ngroups = 4 at bench shape, no tail
    gnll_stage1<<<grid, block, 0, stream>>>(yp, yt, lsv, lsu, partials, n4);
    gnll_stage2<<<1, block, 0, stream>>>(partials, out, grid, neg_inv_n);
}